// Round 2
// baseline (21786.189 us; speedup 1.0000x reference)
//
#include <hip/hip_runtime.h>
#include <hip/hip_bf16.h>

typedef __bf16 bf16x8 __attribute__((ext_vector_type(8)));
typedef float  f32x4  __attribute__((ext_vector_type(4)));
typedef unsigned short u16;
typedef unsigned int   u32;

#define SEQ   512
#define BATCH 64
#define INP   1024
#define HID   1024
#define NBLK  64

// ---- workspace layout (bytes) ----
// wc   : 4096*2048 u16        = 16777216   ([W_ih | W_hh], row n k-contiguous)
// hseq : 513*64*1024 u16      = 67239936   (h[t] gets its OWN buffer -> no stale L2)
// bias : 4096 f32             = 16384
// cnt  : 1 u32
// total 84033540 B  (< round-1's proven 84164612)
#define WC_OFF   0ull
#define HSEQ_OFF (WC_OFF + 16777216ull)
#define BIAS_OFF (HSEQ_OFF + 67239936ull)
#define CNT_OFF  (BIAS_OFF + 16384ull)

__device__ __forceinline__ u16 f2bf(float f) {
    u32 u = __float_as_uint(f);
    u = (u + 0x7FFFu + ((u >> 16) & 1u)) >> 16;
    return (u16)u;
}

__device__ __forceinline__ bf16x8 ld8(const u16* p) {
    return *reinterpret_cast<const bf16x8*>(p);
}

// 8 consecutive fp32 -> bf16x8 (RNE), via packed cvt
__device__ __forceinline__ bf16x8 cvt8(const float* p) {
    float4 lo = *reinterpret_cast<const float4*>(p);
    float4 hi = *reinterpret_cast<const float4*>(p + 4);
    union { __hip_bfloat162 h2[4]; bf16x8 v; } u;
    u.h2[0] = __float22bfloat162_rn(float2{lo.x, lo.y});
    u.h2[1] = __float22bfloat162_rn(float2{lo.z, lo.w});
    u.h2[2] = __float22bfloat162_rn(float2{hi.x, hi.y});
    u.h2[3] = __float22bfloat162_rn(float2{hi.z, hi.w});
    return u.v;
}

__device__ __forceinline__ float sigmoidf_fast(float x) {
    return 1.0f / (1.0f + __expf(-x));
}
__device__ __forceinline__ float tanhf_fast(float x) {
    return 2.0f / (1.0f + __expf(-2.0f * x)) - 1.0f;
}

// ---------------- prep: weights->bf16, bias fuse, h0 zero, cnt zero ----------
__global__ void lstm_prep(const float* __restrict__ wih,
                          const float* __restrict__ whh,
                          const float* __restrict__ bih,
                          const float* __restrict__ bhh,
                          u16* __restrict__ wc, u16* __restrict__ hseq,
                          float* __restrict__ bias, u32* __restrict__ cnt) {
    const long long NW = 8388608ll;    // wc elements (4096*2048)
    const long long NB = 4096ll;
    const long long NH = 65536ll;      // h[0] buffer
    const long long total = NW + NB + NH + 1;
    long long stride = (long long)gridDim.x * blockDim.x;
    for (long long i = (long long)blockIdx.x * blockDim.x + threadIdx.x;
         i < total; i += stride) {
        if (i < NW) {
            long long row = i >> 11;          // /2048
            long long col = i & 2047;
            float v = (col < 1024) ? wih[row * 1024 + col]
                                   : whh[row * 1024 + (col - 1024)];
            wc[i] = f2bf(v);
        } else if (i < NW + NB) {
            long long j = i - NW;
            bias[j] = bih[j] + bhh[j];
        } else if (i < NW + NB + NH) {
            hseq[i - NW - NB] = 0;
        } else {
            cnt[0] = 0;
        }
    }
}

// ---------------- persistent recurrence ----------------
// 64 blocks x 256 threads. Block c owns h-cols [16c, 16c+16).
// Waves 0,1: x_t @ W_ih^T slices (K 0..1024, fp32->bf16 on the fly) — no grid dep,
//            so they run WHILE waves 2,3 wait on the grid barrier.
// Waves 2,3: h[t] @ W_hh^T slices (K 0..1024 of hseq[t], plain cached loads —
//            hseq[t] is a fresh address each step, so no stale-L2 hazard).
// h[t+1] stored with relaxed AGENT-scope u32 atomics (write-through to coherent
// point). Barrier = vmcnt(0) + syncthreads + relaxed agent fetch_add + spin.
// NO __threadfence anywhere -> weights stay L2-resident.
__global__ __launch_bounds__(256, 1) void lstm_rec(
    const float* __restrict__ x, const u16* __restrict__ wc,
    const float* __restrict__ bias, const float* __restrict__ km,
    u16* __restrict__ hseq, float* __restrict__ out,
    u32* __restrict__ cnt, const int* __restrict__ trainp) {

    __shared__ float part[4][4][BATCH][16];  // [wave][gate][b][j] = 64 KB

    const int tid  = threadIdx.x;
    const int w    = tid >> 6;
    const int lane = tid & 63;
    const int quad = lane >> 4;
    const int l16  = lane & 15;
    const int cu   = blockIdx.x;       // 0..63
    const int col0 = cu * 16;

    const int training = trainp[0];
    const float scale = training ? (1.0f / 0.9f) : 1.0f;

    // B (weights): row n = g*1024 + col0 + l16, k = w*512 + kk*32 + quad*8
    const u16* wbase = wc + (size_t)(col0 + l16) * 2048 + (size_t)w * 512
                          + (size_t)quad * 8;

    // cell-update mapping: thread -> cols (cj2, cj2+1), rows b = cb0 + 32r
    const int cj2 = (tid & 7) * 2;
    const int cb0 = tid >> 3;          // 0..31
    float bi[4][2];
    #pragma unroll
    for (int g = 0; g < 4; ++g) {
        bi[g][0] = bias[g * 1024 + col0 + cj2];
        bi[g][1] = bias[g * 1024 + col0 + cj2 + 1];
    }

    float creg[2][2] = {{0.f, 0.f}, {0.f, 0.f}};

    #pragma unroll 1
    for (int t = 0; t < SEQ; ++t) {
        // keep-mask prefetch (independent of barrier)
        float2 kmv[2];
        kmv[0] = *reinterpret_cast<const float2*>(
            &km[(size_t)t * 65536 + (size_t)cb0 * 1024 + col0 + cj2]);
        kmv[1] = *reinterpret_cast<const float2*>(
            &km[(size_t)t * 65536 + (size_t)(cb0 + 32) * 1024 + col0 + cj2]);

        f32x4 acc[4][4];   // [gate][mtile]
        #pragma unroll
        for (int g = 0; g < 4; ++g)
            #pragma unroll
            for (int mt = 0; mt < 4; ++mt)
                acc[g][mt] = (f32x4){0.f, 0.f, 0.f, 0.f};

        if (w < 2) {
            // ---- x-part: no grid dependency ----
            const float* Arow = x + (size_t)t * (BATCH * INP)
                                  + (size_t)l16 * 1024 + (size_t)w * 512
                                  + (size_t)quad * 8;
            #pragma unroll 4
            for (int kk = 0; kk < 16; ++kk) {
                bf16x8 afr[4], bfr[4];
                #pragma unroll
                for (int mt = 0; mt < 4; ++mt)
                    afr[mt] = cvt8(Arow + (size_t)mt * 16 * 1024 + kk * 32);
                #pragma unroll
                for (int g = 0; g < 4; ++g)
                    bfr[g] = ld8(wbase + (size_t)g * 1024 * 2048 + kk * 32);
                #pragma unroll
                for (int g = 0; g < 4; ++g)
                    #pragma unroll
                    for (int mt = 0; mt < 4; ++mt)
                        acc[g][mt] = __builtin_amdgcn_mfma_f32_16x16x32_bf16(
                            afr[mt], bfr[g], acc[g][mt], 0, 0, 0);
            }
        } else {
            // ---- h-part: wait until all blocks published h[t] ----
            const u32 target = (u32)t * NBLK;
            while (__hip_atomic_load(cnt, __ATOMIC_RELAXED,
                                     __HIP_MEMORY_SCOPE_AGENT) < target) {
                __builtin_amdgcn_s_sleep(1);
            }
            asm volatile("" ::: "memory");   // block compiler hoist of h loads

            const u16* Hrow = hseq + (size_t)t * 65536
                                   + (size_t)l16 * 1024 + (size_t)(w - 2) * 512
                                   + (size_t)quad * 8;
            #pragma unroll 4
            for (int kk = 0; kk < 16; ++kk) {
                bf16x8 afr[4], bfr[4];
                #pragma unroll
                for (int mt = 0; mt < 4; ++mt)
                    afr[mt] = ld8(Hrow + (size_t)mt * 16 * 1024 + kk * 32);
                #pragma unroll
                for (int g = 0; g < 4; ++g)
                    bfr[g] = ld8(wbase + (size_t)g * 1024 * 2048 + kk * 32);
                #pragma unroll
                for (int g = 0; g < 4; ++g)
                    #pragma unroll
                    for (int mt = 0; mt < 4; ++mt)
                        acc[g][mt] = __builtin_amdgcn_mfma_f32_16x16x32_bf16(
                            afr[mt], bfr[g], acc[g][mt], 0, 0, 0);
            }
        }

        // C layout: col = lane&15, row = quad*4 + reg  (per M-tile)
        #pragma unroll
        for (int g = 0; g < 4; ++g)
            #pragma unroll
            for (int mt = 0; mt < 4; ++mt)
                #pragma unroll
                for (int r = 0; r < 4; ++r)
                    part[w][g][mt * 16 + quad * 4 + r][l16] = acc[g][mt][r];

        __syncthreads();

        // ---- cell update: 2 rows x 2 cols per thread ----
        u16* hout = hseq + (size_t)(t + 1) * 65536;
        #pragma unroll
        for (int r = 0; r < 2; ++r) {
            int b = cb0 + 32 * r;
            float hv[2];
            #pragma unroll
            for (int c = 0; c < 2; ++c) {
                int j = cj2 + c;
                float gi = part[0][0][b][j] + part[1][0][b][j]
                         + part[2][0][b][j] + part[3][0][b][j] + bi[0][c];
                float gf = part[0][1][b][j] + part[1][1][b][j]
                         + part[2][1][b][j] + part[3][1][b][j] + bi[1][c];
                float gg = part[0][2][b][j] + part[1][2][b][j]
                         + part[2][2][b][j] + part[3][2][b][j] + bi[2][c];
                float go = part[0][3][b][j] + part[1][3][b][j]
                         + part[2][3][b][j] + part[3][3][b][j] + bi[3][c];

                float ig = sigmoidf_fast(gi);
                float fg = sigmoidf_fast(gf);
                float gt = tanhf_fast(gg);
                float og = sigmoidf_fast(go);

                float cv = fg * creg[r][c] + ig * gt;
                creg[r][c] = cv;
                float h = og * tanhf_fast(cv);
                if (training)
                    h = h * (c ? kmv[r].y : kmv[r].x) * scale;
                hv[c] = h;
            }
            int cidx = b * 1024 + col0 + cj2;
            u32 packed = (u32)f2bf(hv[0]) | ((u32)f2bf(hv[1]) << 16);
            // agent-scope write-through store -> visible at coherent point
            __hip_atomic_store((u32*)(hout + cidx), packed,
                               __ATOMIC_RELAXED, __HIP_MEMORY_SCOPE_AGENT);
            if (t == SEQ - 1) {
                out[cidx]     = hv[0];
                out[cidx + 1] = hv[1];
            }
        }

        // ---- barrier: my h stores acked at coherent point, then count in ----
        asm volatile("s_waitcnt vmcnt(0)" ::: "memory");
        __syncthreads();   // all waves' stores done + part[] reads done
        if (tid == 0) {
            __hip_atomic_fetch_add(cnt, 1u, __ATOMIC_RELAXED,
                                   __HIP_MEMORY_SCOPE_AGENT);
        }
    }
}

extern "C" void kernel_launch(void* const* d_in, const int* in_sizes, int n_in,
                              void* d_out, int out_size, void* d_ws, size_t ws_size,
                              hipStream_t stream) {
    const float* x   = (const float*)d_in[0];
    const float* km  = (const float*)d_in[1];
    const float* wih = (const float*)d_in[2];
    const float* whh = (const float*)d_in[3];
    const float* bih = (const float*)d_in[4];
    const float* bhh = (const float*)d_in[5];
    const int*   tr  = (const int*)d_in[6];
    float* out = (float*)d_out;

    char* ws = (char*)d_ws;
    u16*   wc   = (u16*)(ws + WC_OFF);
    u16*   hseq = (u16*)(ws + HSEQ_OFF);
    float* bias = (float*)(ws + BIAS_OFF);
    u32*   cnt  = (u32*)(ws + CNT_OFF);

    lstm_prep<<<dim3(1024), dim3(256), 0, stream>>>(wih, whh, bih, bhh,
                                                    wc, hseq, bias, cnt);
    lstm_rec<<<dim3(NBLK), dim3(256), 0, stream>>>(x, wc, bias, km, hseq,
                                                   out, cnt, tr);
}

// Round 3
// 14861.931 us; speedup vs baseline: 1.4659x; 1.4659x over previous
//
#include <hip/hip_runtime.h>
#include <hip/hip_bf16.h>

typedef __bf16 bf16x8 __attribute__((ext_vector_type(8)));
typedef float  f32x4  __attribute__((ext_vector_type(4)));
typedef unsigned short u16;
typedef unsigned int   u32;

#define SEQ   512
#define BATCH 64
#define INP   1024
#define HID   1024
#define NBLK  64

// ---- workspace layout (bytes) ----
// wc    : 4096*2048 u16      = 16777216   ([W_ih | W_hh], row n k-contiguous)
// hseq  : 513*64*1024 u16    = 67239936   (h[t] gets its OWN buffer -> no stale L2)
// bias  : 4096 f32           = 16384
// flags : 64 * 32 u32        = 8192       (per-block step counter, 128B apart)
// total 84041728 B (~ round-1's proven 84 MB)
#define WC_OFF    0ull
#define HSEQ_OFF  (WC_OFF + 16777216ull)
#define BIAS_OFF  (HSEQ_OFF + 67239936ull)
#define FLAGS_OFF (BIAS_OFF + 16384ull)

__device__ __forceinline__ u16 f2bf(float f) {
    u32 u = __float_as_uint(f);
    u = (u + 0x7FFFu + ((u >> 16) & 1u)) >> 16;
    return (u16)u;
}

__device__ __forceinline__ bf16x8 ld8(const u16* p) {
    return *reinterpret_cast<const bf16x8*>(p);
}

// 8 consecutive fp32 -> bf16x8 (RNE), via packed cvt
__device__ __forceinline__ bf16x8 cvt8(const float* p) {
    float4 lo = *reinterpret_cast<const float4*>(p);
    float4 hi = *reinterpret_cast<const float4*>(p + 4);
    union { __hip_bfloat162 h2[4]; bf16x8 v; } u;
    u.h2[0] = __float22bfloat162_rn(float2{lo.x, lo.y});
    u.h2[1] = __float22bfloat162_rn(float2{lo.z, lo.w});
    u.h2[2] = __float22bfloat162_rn(float2{hi.x, hi.y});
    u.h2[3] = __float22bfloat162_rn(float2{hi.z, hi.w});
    return u.v;
}

__device__ __forceinline__ float sigmoidf_fast(float x) {
    return 1.0f / (1.0f + __expf(-x));
}
__device__ __forceinline__ float tanhf_fast(float x) {
    return 2.0f / (1.0f + __expf(-2.0f * x)) - 1.0f;
}

// ---------------- prep: weights->bf16, bias fuse, h0 zero, flags zero -------
__global__ void lstm_prep(const float* __restrict__ wih,
                          const float* __restrict__ whh,
                          const float* __restrict__ bih,
                          const float* __restrict__ bhh,
                          u16* __restrict__ wc, u16* __restrict__ hseq,
                          float* __restrict__ bias, u32* __restrict__ flags) {
    const long long NW = 8388608ll;    // wc elements (4096*2048)
    const long long NB = 4096ll;
    const long long NH = 65536ll;      // h[0] buffer
    const long long NF = 2048ll;       // flags area (64*32 u32)
    const long long total = NW + NB + NH + NF;
    long long stride = (long long)gridDim.x * blockDim.x;
    for (long long i = (long long)blockIdx.x * blockDim.x + threadIdx.x;
         i < total; i += stride) {
        if (i < NW) {
            long long row = i >> 11;          // /2048
            long long col = i & 2047;
            float v = (col < 1024) ? wih[row * 1024 + col]
                                   : whh[row * 1024 + (col - 1024)];
            wc[i] = f2bf(v);
        } else if (i < NW + NB) {
            long long j = i - NW;
            bias[j] = bih[j] + bhh[j];
        } else if (i < NW + NB + NH) {
            hseq[i - NW - NB] = 0;
        } else {
            flags[i - NW - NB - NH] = 0;
        }
    }
}

// ---------------- persistent recurrence ----------------
// 64 blocks x 256 threads. Block c owns h/gate-cols [16c, 16c+16).
// Every wave w handles K-slice [256w, 256w+256) of BOTH the x-part (fp32 x,
// cvt on the fly; no grid dependency -> runs in the barrier shadow) and the
// h-part (bf16 hseq[t], fresh address each step -> plain cached loads safe),
// accumulating both into the same acc. Post-barrier critical path = 128 MFMA.
//
// Grid barrier: distributed flags. Arrival: tid0 stores flags[bid]=t+1
// (relaxed agent, write-through) after vmcnt(0)+syncthreads. Detection:
// every wave's lane i loads flags[i] (64 distinct 128B lines, one vector
// load) + __ballot. No atomic RMW, no same-line spin storm.
__global__ __launch_bounds__(256, 1) void lstm_rec(
    const float* __restrict__ x, const u16* __restrict__ wc,
    const float* __restrict__ bias, const float* __restrict__ km,
    u16* __restrict__ hseq, float* __restrict__ out,
    u32* __restrict__ flags, const int* __restrict__ trainp) {

    __shared__ float part[4][4][BATCH][16];  // [wave][gate][b][j] = 64 KB

    const int tid  = threadIdx.x;
    const int w    = tid >> 6;
    const int lane = tid & 63;
    const int quad = lane >> 4;
    const int l16  = lane & 15;
    const int cu   = blockIdx.x;       // 0..63
    const int col0 = cu * 16;

    const int training = trainp[0];
    const float scale = training ? (1.0f / 0.9f) : 1.0f;

    // B (weights): row n = g*1024 + col0 + l16; x-part k = w*256 + kk*32 + quad*8,
    // h-part k = 1024 + same.
    const u16* wbase = wc + (size_t)(col0 + l16) * 2048 + (size_t)w * 256
                          + (size_t)quad * 8;

    // cell-update mapping: thread -> cols (cj2, cj2+1), rows b = cb0 + 32r
    const int cj2 = (tid & 7) * 2;
    const int cb0 = tid >> 3;          // 0..31
    float bi[4][2];
    #pragma unroll
    for (int g = 0; g < 4; ++g) {
        bi[g][0] = bias[g * 1024 + col0 + cj2];
        bi[g][1] = bias[g * 1024 + col0 + cj2 + 1];
    }

    float creg[2][2] = {{0.f, 0.f}, {0.f, 0.f}};

    #pragma unroll 1
    for (int t = 0; t < SEQ; ++t) {
        // keep-mask prefetch: cold HBM loads, issued with maximum lead time
        float2 kmv[2];
        kmv[0] = *reinterpret_cast<const float2*>(
            &km[(size_t)t * 65536 + (size_t)cb0 * 1024 + col0 + cj2]);
        kmv[1] = *reinterpret_cast<const float2*>(
            &km[(size_t)t * 65536 + (size_t)(cb0 + 32) * 1024 + col0 + cj2]);

        f32x4 acc[4][4];   // [gate][mtile]
        #pragma unroll
        for (int g = 0; g < 4; ++g)
            #pragma unroll
            for (int mt = 0; mt < 4; ++mt)
                acc[g][mt] = (f32x4){0.f, 0.f, 0.f, 0.f};

        // ---- x-part (no grid dependency; hides the barrier wait) ----
        {
            const float* Arow = x + (size_t)t * (BATCH * INP)
                                  + (size_t)l16 * 1024 + (size_t)w * 256
                                  + (size_t)quad * 8;
            #pragma unroll 4
            for (int kk = 0; kk < 8; ++kk) {
                bf16x8 afr[4], bfr[4];
                #pragma unroll
                for (int mt = 0; mt < 4; ++mt)
                    afr[mt] = cvt8(Arow + (size_t)mt * 16 * 1024 + kk * 32);
                #pragma unroll
                for (int g = 0; g < 4; ++g)
                    bfr[g] = ld8(wbase + (size_t)g * 1024 * 2048 + kk * 32);
                #pragma unroll
                for (int g = 0; g < 4; ++g)
                    #pragma unroll
                    for (int mt = 0; mt < 4; ++mt)
                        acc[g][mt] = __builtin_amdgcn_mfma_f32_16x16x32_bf16(
                            afr[mt], bfr[g], acc[g][mt], 0, 0, 0);
            }
        }

        // ---- distributed barrier: wait until all blocks published h[t] ----
        if (t > 0) {
            const u32* fl = flags + ((u32)lane << 5);
            while (true) {
                u32 f = __hip_atomic_load(fl, __ATOMIC_RELAXED,
                                          __HIP_MEMORY_SCOPE_AGENT);
                if (__ballot((int)f >= t) == 0xFFFFFFFFFFFFFFFFull) break;
                __builtin_amdgcn_s_sleep(1);
            }
            asm volatile("" ::: "memory");   // block compiler hoist of h loads
        }

        // ---- h-part ----
        {
            const u16* Hrow = hseq + (size_t)t * 65536
                                   + (size_t)l16 * 1024 + (size_t)w * 256
                                   + (size_t)quad * 8;
            #pragma unroll 4
            for (int kk = 0; kk < 8; ++kk) {
                bf16x8 afr[4], bfr[4];
                #pragma unroll
                for (int mt = 0; mt < 4; ++mt)
                    afr[mt] = ld8(Hrow + (size_t)mt * 16 * 1024 + kk * 32);
                #pragma unroll
                for (int g = 0; g < 4; ++g)
                    bfr[g] = ld8(wbase + 1024 + (size_t)g * 1024 * 2048 + kk * 32);
                #pragma unroll
                for (int g = 0; g < 4; ++g)
                    #pragma unroll
                    for (int mt = 0; mt < 4; ++mt)
                        acc[g][mt] = __builtin_amdgcn_mfma_f32_16x16x32_bf16(
                            afr[mt], bfr[g], acc[g][mt], 0, 0, 0);
            }
        }

        // C layout: col = lane&15, row = quad*4 + reg  (per M-tile)
        #pragma unroll
        for (int g = 0; g < 4; ++g)
            #pragma unroll
            for (int mt = 0; mt < 4; ++mt)
                #pragma unroll
                for (int r = 0; r < 4; ++r)
                    part[w][g][mt * 16 + quad * 4 + r][l16] = acc[g][mt][r];

        __syncthreads();

        // ---- cell update: 2 rows x 2 cols per thread ----
        u16* hout = hseq + (size_t)(t + 1) * 65536;
        #pragma unroll
        for (int r = 0; r < 2; ++r) {
            int b = cb0 + 32 * r;
            float hv[2];
            #pragma unroll
            for (int c = 0; c < 2; ++c) {
                int j = cj2 + c;
                float gi = part[0][0][b][j] + part[1][0][b][j]
                         + part[2][0][b][j] + part[3][0][b][j] + bi[0][c];
                float gf = part[0][1][b][j] + part[1][1][b][j]
                         + part[2][1][b][j] + part[3][1][b][j] + bi[1][c];
                float gg = part[0][2][b][j] + part[1][2][b][j]
                         + part[2][2][b][j] + part[3][2][b][j] + bi[2][c];
                float go = part[0][3][b][j] + part[1][3][b][j]
                         + part[2][3][b][j] + part[3][3][b][j] + bi[3][c];

                float ig = sigmoidf_fast(gi);
                float fg = sigmoidf_fast(gf);
                float gt = tanhf_fast(gg);
                float og = sigmoidf_fast(go);

                float cv = fg * creg[r][c] + ig * gt;
                creg[r][c] = cv;
                float h = og * tanhf_fast(cv);
                if (training)
                    h = h * (c ? kmv[r].y : kmv[r].x) * scale;
                hv[c] = h;
            }
            int cidx = b * 1024 + col0 + cj2;
            u32 packed = (u32)f2bf(hv[0]) | ((u32)f2bf(hv[1]) << 16);
            // agent-scope write-through store -> visible at coherent point
            __hip_atomic_store((u32*)(hout + cidx), packed,
                               __ATOMIC_RELAXED, __HIP_MEMORY_SCOPE_AGENT);
            if (t == SEQ - 1) {
                out[cidx]     = hv[0];
                out[cidx + 1] = hv[1];
            }
        }

        // ---- arrive: my stores acked at coherent point, then publish ----
        asm volatile("s_waitcnt vmcnt(0)" ::: "memory");
        __syncthreads();   // all waves' stores drained + part[] reads done
        if (tid == 0) {
            __hip_atomic_store(flags + ((u32)cu << 5), (u32)(t + 1),
                               __ATOMIC_RELAXED, __HIP_MEMORY_SCOPE_AGENT);
        }
    }
}

extern "C" void kernel_launch(void* const* d_in, const int* in_sizes, int n_in,
                              void* d_out, int out_size, void* d_ws, size_t ws_size,
                              hipStream_t stream) {
    const float* x   = (const float*)d_in[0];
    const float* km  = (const float*)d_in[1];
    const float* wih = (const float*)d_in[2];
    const float* whh = (const float*)d_in[3];
    const float* bih = (const float*)d_in[4];
    const float* bhh = (const float*)d_in[5];
    const int*   tr  = (const int*)d_in[6];
    float* out = (float*)d_out;

    char* ws = (char*)d_ws;
    u16*   wc    = (u16*)(ws + WC_OFF);
    u16*   hseq  = (u16*)(ws + HSEQ_OFF);
    float* bias  = (float*)(ws + BIAS_OFF);
    u32*   flags = (u32*)(ws + FLAGS_OFF);

    lstm_prep<<<dim3(1024), dim3(256), 0, stream>>>(wih, whh, bih, bhh,
                                                    wc, hseq, bias, flags);
    lstm_rec<<<dim3(NBLK), dim3(256), 0, stream>>>(x, wc, bias, km, hseq,
                                                   out, flags, tr);
}